// Round 5
// baseline (400.855 us; speedup 1.0000x reference)
//
#include <hip/hip_runtime.h>
#include <stdint.h>

#define Sq   2176
#define Dm   3072
#define NDm  9216
#define NH   24
#define HDm  128
#define BLKR 1152   // S - COND
#define NT   (Sq / 64)   // 34 KV tiles of 64

typedef __attribute__((ext_vector_type(8))) __bf16 bf16x8;
typedef __attribute__((ext_vector_type(4))) float f32x4;
typedef __attribute__((ext_vector_type(8))) unsigned short ushort8;

#define AS1 __attribute__((address_space(1)))
#define AS3 __attribute__((address_space(3)))

__device__ __forceinline__ unsigned short f2bf(float x) {
  unsigned u = __builtin_bit_cast(unsigned, x);
  u += 0x7FFFu + ((u >> 16) & 1u);   // RNE; inputs are finite randoms
  return (unsigned short)(u >> 16);
}

// ---------------- f32 -> bf16 conversion, 8 elems/thread ----------------
__global__ void cvt_kernel(const float* __restrict__ src,
                           unsigned short* __restrict__ dst, int n8) {
  int i = blockIdx.x * blockDim.x + threadIdx.x;
  if (i >= n8) return;
  const float4* s4 = (const float4*)src + (size_t)i * 2;
  float4 a = s4[0], b = s4[1];
  ushort8 o;
  o[0]=f2bf(a.x); o[1]=f2bf(a.y); o[2]=f2bf(a.z); o[3]=f2bf(a.w);
  o[4]=f2bf(b.x); o[5]=f2bf(b.y); o[6]=f2bf(b.z); o[7]=f2bf(b.w);
  *((ushort8*)dst + i) = o;
}

// 3 weight matrices in one launch (blockIdx.y selects source)
__global__ void cvt3_kernel(const float* __restrict__ w0, const float* __restrict__ w1,
                            const float* __restrict__ w2,
                            unsigned short* __restrict__ dst, int n8) {
  int i = blockIdx.x * blockDim.x + threadIdx.x;
  if (i >= n8) return;
  const float* src = blockIdx.y == 0 ? w0 : (blockIdx.y == 1 ? w1 : w2);
  const float4* s4 = (const float4*)src + (size_t)i * 2;
  float4 a = s4[0], b = s4[1];
  ushort8 o;
  o[0]=f2bf(a.x); o[1]=f2bf(a.y); o[2]=f2bf(a.z); o[3]=f2bf(a.w);
  o[4]=f2bf(b.x); o[5]=f2bf(b.y); o[6]=f2bf(b.z); o[7]=f2bf(b.w);
  *((ushort8*)dst + (size_t)blockIdx.y * (Dm * (size_t)Dm / 8) + i) = o;
}

// ---------------- fused QKV GEMM: C[s][n] = sum_e hs[s][e]*W[n][e] + bias ---
// 128x128 tile, 4 waves, BK=32, double-buffered LDS with counted vmcnt
// (T3/T4), g^((g>>3)&7) 16B-unit swizzle (T2, both-sides), dead-Q-block
// skip + bijective XCD chunking (T1). 4 blocks/CU by design.
__global__ __launch_bounds__(256, 4) void gemm_kernel(
    const unsigned short* __restrict__ A,
    const unsigned short* __restrict__ B,
    const float* __restrict__ bq, const float* __restrict__ bk,
    const float* __restrict__ bv, float* __restrict__ C) {
  __shared__ __attribute__((aligned(16))) unsigned short aL[2][128 * 32];
  __shared__ __attribute__((aligned(16))) unsigned short bL[2][128 * 32];
  int t = threadIdx.x;
  int wid = t >> 6, lane = t & 63;
  int lr = lane & 15, lg = lane >> 4;
  int wr = wid >> 1, wc = wid & 1;

  // grid remap: 1032 blocks = 8 XCD chunks x 129.
  // Q region (n-tiles 0..23): m-tiles 0..8 only (rows >=1152 of Q unused).
  int bid = blockIdx.x;
  int wg = (bid & 7) * 129 + (bid >> 3);
  int mt, nt;
  if (wg < 216) { nt = wg / 9; mt = wg % 9; }
  else { int r2 = wg - 216; nt = 24 + r2 / 17; mt = r2 % 17; }
  int m0 = mt * 128, n0 = nt * 128;

  f32x4 acc[4][4];
#pragma unroll
  for (int m = 0; m < 4; m++)
#pragma unroll
    for (int n = 0; n < 4; n++) acc[m][n] = (f32x4){0.f, 0.f, 0.f, 0.f};

  // staging sources: pre-swizzled per lane (16B unit g <- logical gl)
  const unsigned short* sA[2];
  const unsigned short* sB[2];
#pragma unroll
  for (int c = 0; c < 2; c++) {
    int g = c * 256 + t;
    int gl = g ^ ((g >> 3) & 7);
    int rr = gl >> 2, uu = gl & 3;
    sA[c] = A + (size_t)(m0 + rr) * Dm + uu * 8;
    sB[c] = B + (size_t)(n0 + rr) * Dm + uu * 8;
  }

  // ds_read offsets (elems), swizzled to match
  int offA[4], offB[4];
#pragma unroll
  for (int m = 0; m < 4; m++) {
    int r = wr * 64 + m * 16 + lr;
    int g = r * 4 + lg;
    offA[m] = (g ^ ((g >> 3) & 7)) * 8;
  }
#pragma unroll
  for (int n = 0; n < 4; n++) {
    int r = wc * 64 + n * 16 + lr;
    int g = r * 4 + lg;
    offB[n] = (g ^ ((g >> 3) & 7)) * 8;
  }

  auto stage = [&](int kt, int buf) {
    const int ko = kt * 32;
#pragma unroll
    for (int c = 0; c < 2; c++) {
      __builtin_amdgcn_global_load_lds(
          (const AS1 void*)(sA[c] + ko),
          (AS3 void*)(&aL[buf][c * 2048 + wid * 512]), 16, 0, 0);
      __builtin_amdgcn_global_load_lds(
          (const AS1 void*)(sB[c] + ko),
          (AS3 void*)(&bL[buf][c * 2048 + wid * 512]), 16, 0, 0);
    }
  };

  auto compute = [&](int buf) {
    bf16x8 af[4], bf[4];
#pragma unroll
    for (int m = 0; m < 4; m++) af[m] = *(const bf16x8*)&aL[buf][offA[m]];
#pragma unroll
    for (int n = 0; n < 4; n++) bf[n] = *(const bf16x8*)&bL[buf][offB[n]];
    __builtin_amdgcn_s_setprio(1);
#pragma unroll
    for (int m = 0; m < 4; m++)
#pragma unroll
      for (int n = 0; n < 4; n++)
        acc[m][n] = __builtin_amdgcn_mfma_f32_16x16x32_bf16(af[m], bf[n], acc[m][n], 0, 0, 0);
    __builtin_amdgcn_s_setprio(0);
  };

  stage(0, 0);
  for (int it = 0; it < 95; ++it) {
    stage(it + 1, (it + 1) & 1);
    asm volatile("s_waitcnt vmcnt(4)" ::: "memory");   // current tile landed; next stays in flight
    __builtin_amdgcn_s_barrier();
    compute(it & 1);
    asm volatile("s_waitcnt lgkmcnt(0)" ::: "memory"); // reads done before buffer reuse
    __builtin_amdgcn_s_barrier();
  }
  asm volatile("s_waitcnt vmcnt(0)" ::: "memory");
  __builtin_amdgcn_s_barrier();
  compute(1);

#pragma unroll
  for (int m = 0; m < 4; m++)
#pragma unroll
    for (int n = 0; n < 4; n++) {
      int col = n0 + wc * 64 + n * 16 + lr;
      float bias = col < 3072 ? bq[col] : (col < 6144 ? bk[col - 3072] : bv[col - 6144]);
#pragma unroll
      for (int i = 0; i < 4; i++) {
        int r = m0 + wr * 64 + m * 16 + lg * 4 + i;
        C[(size_t)r * NDm + col] = acc[m][n][i] + bias;
      }
    }
}

// ---------------- LoRA for k,v only (q LoRA only touches discarded rows) ---
__global__ __launch_bounds__(256) void lora_kernel(
    const float* __restrict__ hs,
    const float* __restrict__ k_down, const float* __restrict__ k_up,
    const float* __restrict__ v_down, const float* __restrict__ v_up,
    float* __restrict__ qkv) {
  int srow = BLKR + blockIdx.x;
  int t = threadIdx.x;
  __shared__ float hsl[Dm];
  __shared__ float tl[32];
  for (int e = t; e < Dm; e += 256) hsl[e] = hs[(size_t)srow * Dm + e];
  __syncthreads();
  int dot = t >> 3, part = t & 7;
  int mat = dot >> 4, j = dot & 15;
  const float* down = mat ? v_down : k_down;
  float p = 0.f;
  for (int e = part; e < Dm; e += 8) p += hsl[e] * down[j * Dm + e];
  p += __shfl_xor(p, 1, 64);
  p += __shfl_xor(p, 2, 64);
  p += __shfl_xor(p, 4, 64);
  if (part == 0) tl[dot] = p;
  __syncthreads();
  float tk[16], tv[16];
#pragma unroll
  for (int jj = 0; jj < 16; jj++) { tk[jj] = tl[jj]; tv[jj] = tl[16 + jj]; }
  for (int n = t; n < Dm; n += 256) {
    float ak = 0.f, av = 0.f;
#pragma unroll
    for (int jj = 0; jj < 16; jj++) {
      ak += tk[jj] * k_up[n * 16 + jj];
      av += tv[jj] * v_up[n * 16 + jj];
    }
    qkv[(size_t)srow * NDm + 3072 + n] += ak;
    qkv[(size_t)srow * NDm + 6144 + n] += av;
  }
}

// ---------------- RMSNorm + RoPE -> bf16 head-major q,k ----------------
__global__ __launch_bounds__(64) void prep_kernel(
    const float* __restrict__ qkv,
    const float* __restrict__ nqw, const float* __restrict__ nkw,
    const float* __restrict__ rc, const float* __restrict__ rs,
    unsigned short* __restrict__ qh, unsigned short* __restrict__ kh) {
  int s = blockIdx.x, h = blockIdx.y;
  int l = threadIdx.x;
  int d0 = l * 2;
  float c0 = rc[s * 128 + d0], c1 = rc[s * 128 + d0 + 1];
  float s0 = rs[s * 128 + d0], s1 = rs[s * 128 + d0 + 1];

  { // k: all rows
    const float* kp = qkv + (size_t)s * NDm + 3072 + h * 128;
    float2 x = *(const float2*)(kp + d0);
    float ss = x.x * x.x + x.y * x.y;
#pragma unroll
    for (int m = 1; m < 64; m <<= 1) ss += __shfl_xor(ss, m, 64);
    float r = rsqrtf(ss * (1.f / 128.f) + 1e-6f);
    float xn0 = x.x * r * nkw[d0], xn1 = x.y * r * nkw[d0 + 1];
    ushort2 o = make_ushort2(f2bf(xn0 * c0 - xn1 * s0), f2bf(xn1 * c1 + xn0 * s1));
    *(ushort2*)&kh[((size_t)h * Sq + s) * 128 + d0] = o;
  }
  if (s < BLKR) { // q: only output rows
    const float* qp = qkv + (size_t)s * NDm + h * 128;
    float2 x = *(const float2*)(qp + d0);
    float ss = x.x * x.x + x.y * x.y;
#pragma unroll
    for (int m = 1; m < 64; m <<= 1) ss += __shfl_xor(ss, m, 64);
    float r = rsqrtf(ss * (1.f / 128.f) + 1e-6f);
    float xn0 = x.x * r * nqw[d0], xn1 = x.y * r * nqw[d0 + 1];
    ushort2 o = make_ushort2(f2bf(xn0 * c0 - xn1 * s0), f2bf(xn1 * c1 + xn0 * s1));
    *(ushort2*)&qh[((size_t)h * BLKR + s) * 128 + d0] = o;
  }
}

// ---------------- v transpose to V^T per head (bf16) ----------------
__global__ __launch_bounds__(256) void vt_kernel(const float* __restrict__ qkv,
                                                 unsigned short* __restrict__ vt) {
  int st = blockIdx.x, dt = blockIdx.y, h = blockIdx.z;
  int tx = threadIdx.x & 31, ty = threadIdx.x >> 5;
  __shared__ float ld[32][33];
  int s0 = st * 32, d0 = dt * 32;
#pragma unroll
  for (int p = 0; p < 4; p++) {
    int ss = ty + p * 8;
    ld[ss][tx] = qkv[(size_t)(s0 + ss) * NDm + 6144 + h * 128 + d0 + tx];
  }
  __syncthreads();
#pragma unroll
  for (int p = 0; p < 4; p++) {
    int dd = ty + p * 8;
    vt[((size_t)h * 128 + d0 + dd) * Sq + s0 + tx] = f2bf(ld[tx][dd]);
  }
}

// ---------------- flash attention: LDS-staged, double-buffered ----------
__global__ __launch_bounds__(256) void attn_kernel(
    const unsigned short* __restrict__ qh,  // [NH][1152][128]
    const unsigned short* __restrict__ kh,  // [NH][2176][128]
    const unsigned short* __restrict__ vt,  // [NH][128][2176]
    float* __restrict__ out) {              // [1152][3072] f32
  int id = blockIdx.x;
  int wg = (id & 7) * 54 + (id >> 3);
  int h = wg / 18, qt = wg % 18;
  int q0 = qt * 64;

  int t = threadIdx.x;
  int w = t >> 6, lane = t & 63;
  int lr = lane & 15, lg = lane >> 4;

  __shared__ __attribute__((aligned(16))) unsigned short kLds[2][64 * 128];
  __shared__ __attribute__((aligned(16))) unsigned short vLds[2][128 * 64];
  __shared__ __attribute__((aligned(16))) unsigned short pl[4][16][72];

  const unsigned short* qb = qh + ((size_t)h * BLKR + q0 + w * 16) * 128;
  bf16x8 aq[4];
#pragma unroll
  for (int m = 0; m < 4; m++)
    aq[m] = *(const bf16x8*)(qb + (size_t)lr * 128 + m * 32 + lg * 8);

  const unsigned short* kh_h = kh + (size_t)h * Sq * 128;
  const unsigned short* vt_h = vt + (size_t)h * 128 * Sq;
  int l16 = lane >> 4, s16 = lane & 15;
  int l8 = lane >> 3, s8 = lane & 7;
  const unsigned short* srcK[4];
  const unsigned short* srcV[4];
  int kRowB[4], vRowB[4];
#pragma unroll
  for (int c = 0; c < 4; c++) {
    int rK = w * 16 + c * 4 + l16;
    srcK[c] = kh_h + (size_t)rK * 128 + ((s16 ^ (rK & 7)) * 8);
    kRowB[c] = (w * 16 + c * 4) * 128;
    int rV = (w * 4 + c) * 8 + l8;
    srcV[c] = vt_h + (size_t)rV * Sq + ((s8 ^ (rV & 7)) * 8);
    vRowB[c] = (w * 4 + c) * 512;
  }

  auto stage = [&](int kt, int buf) {
#pragma unroll
    for (int c = 0; c < 4; c++)
      __builtin_amdgcn_global_load_lds(
          (const AS1 void*)(srcK[c] + (size_t)kt * 8192),
          (AS3 void*)(&kLds[buf][kRowB[c]]), 16, 0, 0);
#pragma unroll
    for (int c = 0; c < 4; c++)
      __builtin_amdgcn_global_load_lds(
          (const AS1 void*)(srcV[c] + (size_t)kt * 64),
          (AS3 void*)(&vLds[buf][vRowB[c]]), 16, 0, 0);
  };

  f32x4 acc[8];
#pragma unroll
  for (int o = 0; o < 8; o++) acc[o] = (f32x4){0.f, 0.f, 0.f, 0.f};
  float lsum[4] = {0.f, 0.f, 0.f, 0.f};
  float M = -3.0e38f;
  const float sc = 0.08838834764831845f;
  const float L2E = 1.4426950408889634f;

  int lr7 = lr & 7;

  auto compute = [&](int buf) {
    const unsigned short* kbuf = kLds[buf];
    const unsigned short* vbuf = vLds[buf];
    f32x4 s2[4];
#pragma unroll
    for (int tt = 0; tt < 4; tt++) s2[tt] = (f32x4){0.f, 0.f, 0.f, 0.f};
#pragma unroll
    for (int tt = 0; tt < 4; tt++)
#pragma unroll
      for (int m = 0; m < 4; m++) {
        bf16x8 kf = *(const bf16x8*)&kbuf[(tt * 16 + lr) * 128 + ((m * 4 + lg) ^ lr7) * 8];
        s2[tt] = __builtin_amdgcn_mfma_f32_16x16x32_bf16(aq[m], kf, s2[tt], 0, 0, 0);
      }
    float tm = -3.0e38f;
#pragma unroll
    for (int tt = 0; tt < 4; tt++)
#pragma unroll
      for (int i = 0; i < 4; i++) tm = fmaxf(tm, s2[tt][i]);
#pragma unroll
    for (int d = 1; d < 64; d <<= 1) tm = fmaxf(tm, __shfl_xor(tm, d, 64));
    tm *= sc;
    if (tm > M + 8.0f) {
      float r = exp2f((M - tm) * L2E);
      M = tm;
#pragma unroll
      for (int o = 0; o < 8; o++)
#pragma unroll
        for (int i = 0; i < 4; i++) acc[o][i] *= r;
#pragma unroll
      for (int i = 0; i < 4; i++) lsum[i] *= r;
    }
    float ea = sc * L2E, eb = -M * L2E;
#pragma unroll
    for (int tt = 0; tt < 4; tt++)
#pragma unroll
      for (int i = 0; i < 4; i++) {
        float p = exp2f(fmaf(s2[tt][i], ea, eb));
        lsum[i] += p;
        pl[w][lg * 4 + i][tt * 16 + lr] = f2bf(p);
      }
    bf16x8 ap0 = *(const bf16x8*)&pl[w][lr][lg * 8];
    bf16x8 ap1 = *(const bf16x8*)&pl[w][lr][32 + lg * 8];
#pragma unroll
    for (int o = 0; o < 8; o++) {
      bf16x8 vf0 = *(const bf16x8*)&vbuf[(o * 16 + lr) * 64 + (lg ^ lr7) * 8];
      bf16x8 vf1 = *(const bf16x8*)&vbuf[(o * 16 + lr) * 64 + ((4 + lg) ^ lr7) * 8];
      acc[o] = __builtin_amdgcn_mfma_f32_16x16x32_bf16(ap0, vf0, acc[o], 0, 0, 0);
      acc[o] = __builtin_amdgcn_mfma_f32_16x16x32_bf16(ap1, vf1, acc[o], 0, 0, 0);
    }
  };

  stage(0, 0);
  __syncthreads();
  for (int kt = 0; kt < NT; kt += 2) {
    stage(kt + 1, 1);
    compute(0);
    __syncthreads();
    if (kt + 2 < NT) stage(kt + 2, 0);
    compute(1);
    __syncthreads();
  }

#pragma unroll
  for (int i = 0; i < 4; i++) {
#pragma unroll
    for (int d = 1; d < 16; d <<= 1) lsum[i] += __shfl_xor(lsum[i], d, 64);
    lsum[i] = 1.f / lsum[i];
  }
#pragma unroll
  for (int o = 0; o < 8; o++) {
    int col = h * 128 + o * 16 + lr;
#pragma unroll
    for (int i = 0; i < 4; i++) {
      int r = q0 + w * 16 + lg * 4 + i;
      out[(size_t)r * 3072 + col] = acc[o][i] * lsum[i];
    }
  }
}

extern "C" void kernel_launch(void* const* d_in, const int* in_sizes, int n_in,
                              void* d_out, int out_size, void* d_ws, size_t ws_size,
                              hipStream_t stream) {
  const float* hs  = (const float*)d_in[0];
  const float* Wq  = (const float*)d_in[1];
  const float* bq  = (const float*)d_in[2];
  const float* Wk  = (const float*)d_in[3];
  const float* bk  = (const float*)d_in[4];
  const float* Wv  = (const float*)d_in[5];
  const float* bv  = (const float*)d_in[6];
  const float* k_down = (const float*)d_in[9];
  const float* k_up   = (const float*)d_in[10];
  const float* v_down = (const float*)d_in[11];
  const float* v_up   = (const float*)d_in[12];
  const float* nqw = (const float*)d_in[13];
  const float* nkw = (const float*)d_in[14];
  const float* rc  = (const float*)d_in[15];
  const float* rsn = (const float*)d_in[16];
  float* out = (float*)d_out;

  char* ws = (char*)d_ws;
  unsigned short* hsb = (unsigned short*)(ws + 0);          // 13,369,344 B
  unsigned short* wb  = (unsigned short*)(ws + 13369344);   // 56,623,104 B
  float*          qkv = (float*)(ws + 69992448);            // 80,216,064 B
  unsigned short* qh  = (unsigned short*)(ws + 150208512);  //  7,077,888 B
  unsigned short* kh  = (unsigned short*)(ws + 157286400);  // 13,369,344 B
  unsigned short* vtb = (unsigned short*)(ws + 170655744);  // 13,369,344 B

  const int n8_hs = Sq * Dm / 8;
  const int n8_w  = Dm * Dm / 8;
  cvt_kernel<<<dim3((n8_hs + 255) / 256), 256, 0, stream>>>(hs, hsb, n8_hs);
  cvt3_kernel<<<dim3((n8_w + 255) / 256, 3), 256, 0, stream>>>(Wq, Wk, Wv, wb, n8_w);

  gemm_kernel<<<dim3(1032), 256, 0, stream>>>(hsb, wb, bq, bk, bv, qkv);
  lora_kernel<<<dim3(Sq - BLKR), 256, 0, stream>>>(hs, k_down, k_up, v_down, v_up, qkv);
  prep_kernel<<<dim3(Sq, NH), 64, 0, stream>>>(qkv, nqw, nkw, rc, rsn, qh, kh);
  vt_kernel<<<dim3(Sq / 32, HDm / 32, NH), 256, 0, stream>>>(qkv, vtb);
  attn_kernel<<<dim3(18 * NH), 256, 0, stream>>>(qh, kh, vtb, out);
}

// Round 6
// 400.237 us; speedup vs baseline: 1.0015x; 1.0015x over previous
//
#include <hip/hip_runtime.h>
#include <stdint.h>

#define Sq   2176
#define Dm   3072
#define NDm  9216
#define NH   24
#define HDm  128
#define BLKR 1152   // S - COND
#define NT   (Sq / 64)   // 34 KV tiles of 64

typedef __attribute__((ext_vector_type(8))) __bf16 bf16x8;
typedef __attribute__((ext_vector_type(4))) float f32x4;
typedef __attribute__((ext_vector_type(8))) unsigned short ushort8;

#define AS1 __attribute__((address_space(1)))
#define AS3 __attribute__((address_space(3)))

__device__ __forceinline__ unsigned short f2bf(float x) {
  unsigned u = __builtin_bit_cast(unsigned, x);
  u += 0x7FFFu + ((u >> 16) & 1u);   // RNE; inputs are finite randoms
  return (unsigned short)(u >> 16);
}

// ---------------- f32 -> bf16 conversion, 8 elems/thread ----------------
__global__ void cvt_kernel(const float* __restrict__ src,
                           unsigned short* __restrict__ dst, int n8) {
  int i = blockIdx.x * blockDim.x + threadIdx.x;
  if (i >= n8) return;
  const float4* s4 = (const float4*)src + (size_t)i * 2;
  float4 a = s4[0], b = s4[1];
  ushort8 o;
  o[0]=f2bf(a.x); o[1]=f2bf(a.y); o[2]=f2bf(a.z); o[3]=f2bf(a.w);
  o[4]=f2bf(b.x); o[5]=f2bf(b.y); o[6]=f2bf(b.z); o[7]=f2bf(b.w);
  *((ushort8*)dst + i) = o;
}

// 3 weight matrices in one launch (blockIdx.y selects source)
__global__ void cvt3_kernel(const float* __restrict__ w0, const float* __restrict__ w1,
                            const float* __restrict__ w2,
                            unsigned short* __restrict__ dst, int n8) {
  int i = blockIdx.x * blockDim.x + threadIdx.x;
  if (i >= n8) return;
  const float* src = blockIdx.y == 0 ? w0 : (blockIdx.y == 1 ? w1 : w2);
  const float4* s4 = (const float4*)src + (size_t)i * 2;
  float4 a = s4[0], b = s4[1];
  ushort8 o;
  o[0]=f2bf(a.x); o[1]=f2bf(a.y); o[2]=f2bf(a.z); o[3]=f2bf(a.w);
  o[4]=f2bf(b.x); o[5]=f2bf(b.y); o[6]=f2bf(b.z); o[7]=f2bf(b.w);
  *((ushort8*)dst + (size_t)blockIdx.y * (Dm * (size_t)Dm / 8) + i) = o;
}

// ---------------- fused QKV GEMM: C[s][n] = sum_e hs[s][e]*W[n][e] + bias ---
// 128x128 tile, 4 waves, BK=32. Round-4 proven 2-barrier single-buffer
// structure (677 TF rate) + dead-Q-block skip + involution LDS swizzle
// (conflicts=0) + n-fastest-within-XCD-chunk mapping (A-panel L2 reuse).
__global__ __launch_bounds__(256) void gemm_kernel(
    const unsigned short* __restrict__ A,
    const unsigned short* __restrict__ B,
    const float* __restrict__ bq, const float* __restrict__ bk,
    const float* __restrict__ bv, float* __restrict__ C) {
  __shared__ __attribute__((aligned(16))) unsigned short aL[128 * 32];
  __shared__ __attribute__((aligned(16))) unsigned short bL[128 * 32];
  int t = threadIdx.x;
  int wid = t >> 6, lane = t & 63;
  int lr = lane & 15, lg = lane >> 4;
  int wr = wid >> 1, wc = wid & 1;

  // grid remap: 1032 blocks = 8 XCD chunks x 129, n-fastest within chunk.
  // Q cols (nt 0..23): m-tiles 0..8 only (Q rows >=1152 are never read).
  int bid = blockIdx.x;
  int wg = (bid & 7) * 129 + (bid >> 3);
  int mt, nt;
  if (wg < 216) { mt = wg / 24; nt = wg % 24; }
  else { int r2 = wg - 216; mt = r2 / 48; nt = 24 + r2 % 48; }
  int m0 = mt * 128, n0 = nt * 128;

  f32x4 acc[4][4];
#pragma unroll
  for (int m = 0; m < 4; m++)
#pragma unroll
    for (int n = 0; n < 4; n++) acc[m][n] = (f32x4){0.f, 0.f, 0.f, 0.f};

  // staging sources: pre-swizzled per lane (16B-unit involution g ^= (g>>3)&7)
  const unsigned short* sA[2];
  const unsigned short* sB[2];
#pragma unroll
  for (int c = 0; c < 2; c++) {
    int g = c * 256 + t;
    int gl = g ^ ((g >> 3) & 7);
    int rr = gl >> 2, uu = gl & 3;
    sA[c] = A + (size_t)(m0 + rr) * Dm + uu * 8;
    sB[c] = B + (size_t)(n0 + rr) * Dm + uu * 8;
  }

  // ds_read offsets (elems), same involution on the logical index
  int offA[4], offB[4];
#pragma unroll
  for (int m = 0; m < 4; m++) {
    int r = wr * 64 + m * 16 + lr;
    int g = r * 4 + lg;
    offA[m] = (g ^ ((g >> 3) & 7)) * 8;
  }
#pragma unroll
  for (int n = 0; n < 4; n++) {
    int r = wc * 64 + n * 16 + lr;
    int g = r * 4 + lg;
    offB[n] = (g ^ ((g >> 3) & 7)) * 8;
  }

  for (int kt = 0; kt < Dm / 32; kt++) {
    const int ko = kt * 32;
#pragma unroll
    for (int c = 0; c < 2; c++) {
      __builtin_amdgcn_global_load_lds(
          (const AS1 void*)(sA[c] + ko),
          (AS3 void*)(&aL[c * 2048 + wid * 512]), 16, 0, 0);
      __builtin_amdgcn_global_load_lds(
          (const AS1 void*)(sB[c] + ko),
          (AS3 void*)(&bL[c * 2048 + wid * 512]), 16, 0, 0);
    }
    __syncthreads();   // compiler drains vmcnt(0) -> LDS tile ready

    bf16x8 af[4], bf[4];
#pragma unroll
    for (int m = 0; m < 4; m++) af[m] = *(const bf16x8*)&aL[offA[m]];
#pragma unroll
    for (int n = 0; n < 4; n++) bf[n] = *(const bf16x8*)&bL[offB[n]];
#pragma unroll
    for (int m = 0; m < 4; m++)
#pragma unroll
      for (int n = 0; n < 4; n++)
        acc[m][n] = __builtin_amdgcn_mfma_f32_16x16x32_bf16(af[m], bf[n], acc[m][n], 0, 0, 0);
    __syncthreads();   // protect LDS before next stage
  }

#pragma unroll
  for (int m = 0; m < 4; m++)
#pragma unroll
    for (int n = 0; n < 4; n++) {
      int col = n0 + wc * 64 + n * 16 + lr;
      float bias = col < 3072 ? bq[col] : (col < 6144 ? bk[col - 3072] : bv[col - 6144]);
#pragma unroll
      for (int i = 0; i < 4; i++) {
        int r = m0 + wr * 64 + m * 16 + lg * 4 + i;
        C[(size_t)r * NDm + col] = acc[m][n][i] + bias;
      }
    }
}

// ---------------- LoRA for k,v only (q LoRA only touches discarded rows) ---
__global__ __launch_bounds__(256) void lora_kernel(
    const float* __restrict__ hs,
    const float* __restrict__ k_down, const float* __restrict__ k_up,
    const float* __restrict__ v_down, const float* __restrict__ v_up,
    float* __restrict__ qkv) {
  int srow = BLKR + blockIdx.x;
  int t = threadIdx.x;
  __shared__ float hsl[Dm];
  __shared__ float tl[32];
  for (int e = t; e < Dm; e += 256) hsl[e] = hs[(size_t)srow * Dm + e];
  __syncthreads();
  int dot = t >> 3, part = t & 7;
  int mat = dot >> 4, j = dot & 15;
  const float* down = mat ? v_down : k_down;
  float p = 0.f;
  for (int e = part; e < Dm; e += 8) p += hsl[e] * down[j * Dm + e];
  p += __shfl_xor(p, 1, 64);
  p += __shfl_xor(p, 2, 64);
  p += __shfl_xor(p, 4, 64);
  if (part == 0) tl[dot] = p;
  __syncthreads();
  float tk[16], tv[16];
#pragma unroll
  for (int jj = 0; jj < 16; jj++) { tk[jj] = tl[jj]; tv[jj] = tl[16 + jj]; }
  for (int n = t; n < Dm; n += 256) {
    float ak = 0.f, av = 0.f;
#pragma unroll
    for (int jj = 0; jj < 16; jj++) {
      ak += tk[jj] * k_up[n * 16 + jj];
      av += tv[jj] * v_up[n * 16 + jj];
    }
    qkv[(size_t)srow * NDm + 3072 + n] += ak;
    qkv[(size_t)srow * NDm + 6144 + n] += av;
  }
}

// ---------------- RMSNorm + RoPE -> bf16 head-major q,k ----------------
__global__ __launch_bounds__(64) void prep_kernel(
    const float* __restrict__ qkv,
    const float* __restrict__ nqw, const float* __restrict__ nkw,
    const float* __restrict__ rc, const float* __restrict__ rs,
    unsigned short* __restrict__ qh, unsigned short* __restrict__ kh) {
  int s = blockIdx.x, h = blockIdx.y;
  int l = threadIdx.x;
  int d0 = l * 2;
  float c0 = rc[s * 128 + d0], c1 = rc[s * 128 + d0 + 1];
  float s0 = rs[s * 128 + d0], s1 = rs[s * 128 + d0 + 1];

  { // k: all rows
    const float* kp = qkv + (size_t)s * NDm + 3072 + h * 128;
    float2 x = *(const float2*)(kp + d0);
    float ss = x.x * x.x + x.y * x.y;
#pragma unroll
    for (int m = 1; m < 64; m <<= 1) ss += __shfl_xor(ss, m, 64);
    float r = rsqrtf(ss * (1.f / 128.f) + 1e-6f);
    float xn0 = x.x * r * nkw[d0], xn1 = x.y * r * nkw[d0 + 1];
    ushort2 o = make_ushort2(f2bf(xn0 * c0 - xn1 * s0), f2bf(xn1 * c1 + xn0 * s1));
    *(ushort2*)&kh[((size_t)h * Sq + s) * 128 + d0] = o;
  }
  if (s < BLKR) { // q: only output rows
    const float* qp = qkv + (size_t)s * NDm + h * 128;
    float2 x = *(const float2*)(qp + d0);
    float ss = x.x * x.x + x.y * x.y;
#pragma unroll
    for (int m = 1; m < 64; m <<= 1) ss += __shfl_xor(ss, m, 64);
    float r = rsqrtf(ss * (1.f / 128.f) + 1e-6f);
    float xn0 = x.x * r * nqw[d0], xn1 = x.y * r * nqw[d0 + 1];
    ushort2 o = make_ushort2(f2bf(xn0 * c0 - xn1 * s0), f2bf(xn1 * c1 + xn0 * s1));
    *(ushort2*)&qh[((size_t)h * BLKR + s) * 128 + d0] = o;
  }
}

// ---------------- v transpose to V^T per head (bf16) ----------------
__global__ __launch_bounds__(256) void vt_kernel(const float* __restrict__ qkv,
                                                 unsigned short* __restrict__ vt) {
  int st = blockIdx.x, dt = blockIdx.y, h = blockIdx.z;
  int tx = threadIdx.x & 31, ty = threadIdx.x >> 5;
  __shared__ float ld[32][33];
  int s0 = st * 32, d0 = dt * 32;
#pragma unroll
  for (int p = 0; p < 4; p++) {
    int ss = ty + p * 8;
    ld[ss][tx] = qkv[(size_t)(s0 + ss) * NDm + 6144 + h * 128 + d0 + tx];
  }
  __syncthreads();
#pragma unroll
  for (int p = 0; p < 4; p++) {
    int dd = ty + p * 8;
    vt[((size_t)h * 128 + d0 + dd) * Sq + s0 + tx] = f2bf(ld[tx][dd]);
  }
}

// ---------------- flash attention: LDS-staged, double-buffered ----------
__global__ __launch_bounds__(256) void attn_kernel(
    const unsigned short* __restrict__ qh,  // [NH][1152][128]
    const unsigned short* __restrict__ kh,  // [NH][2176][128]
    const unsigned short* __restrict__ vt,  // [NH][128][2176]
    float* __restrict__ out) {              // [1152][3072] f32
  int id = blockIdx.x;
  int wg = (id & 7) * 54 + (id >> 3);
  int h = wg / 18, qt = wg % 18;
  int q0 = qt * 64;

  int t = threadIdx.x;
  int w = t >> 6, lane = t & 63;
  int lr = lane & 15, lg = lane >> 4;

  __shared__ __attribute__((aligned(16))) unsigned short kLds[2][64 * 128];
  __shared__ __attribute__((aligned(16))) unsigned short vLds[2][128 * 64];
  __shared__ __attribute__((aligned(16))) unsigned short pl[4][16][72];

  const unsigned short* qb = qh + ((size_t)h * BLKR + q0 + w * 16) * 128;
  bf16x8 aq[4];
#pragma unroll
  for (int m = 0; m < 4; m++)
    aq[m] = *(const bf16x8*)(qb + (size_t)lr * 128 + m * 32 + lg * 8);

  const unsigned short* kh_h = kh + (size_t)h * Sq * 128;
  const unsigned short* vt_h = vt + (size_t)h * 128 * Sq;
  int l16 = lane >> 4, s16 = lane & 15;
  int l8 = lane >> 3, s8 = lane & 7;
  const unsigned short* srcK[4];
  const unsigned short* srcV[4];
  int kRowB[4], vRowB[4];
#pragma unroll
  for (int c = 0; c < 4; c++) {
    int rK = w * 16 + c * 4 + l16;
    srcK[c] = kh_h + (size_t)rK * 128 + ((s16 ^ (rK & 7)) * 8);
    kRowB[c] = (w * 16 + c * 4) * 128;
    int rV = (w * 4 + c) * 8 + l8;
    srcV[c] = vt_h + (size_t)rV * Sq + ((s8 ^ (rV & 7)) * 8);
    vRowB[c] = (w * 4 + c) * 512;
  }

  auto stage = [&](int kt, int buf) {
#pragma unroll
    for (int c = 0; c < 4; c++)
      __builtin_amdgcn_global_load_lds(
          (const AS1 void*)(srcK[c] + (size_t)kt * 8192),
          (AS3 void*)(&kLds[buf][kRowB[c]]), 16, 0, 0);
#pragma unroll
    for (int c = 0; c < 4; c++)
      __builtin_amdgcn_global_load_lds(
          (const AS1 void*)(srcV[c] + (size_t)kt * 64),
          (AS3 void*)(&vLds[buf][vRowB[c]]), 16, 0, 0);
  };

  f32x4 acc[8];
#pragma unroll
  for (int o = 0; o < 8; o++) acc[o] = (f32x4){0.f, 0.f, 0.f, 0.f};
  float lsum[4] = {0.f, 0.f, 0.f, 0.f};
  float M = -3.0e38f;
  const float sc = 0.08838834764831845f;
  const float L2E = 1.4426950408889634f;

  int lr7 = lr & 7;

  auto compute = [&](int buf) {
    const unsigned short* kbuf = kLds[buf];
    const unsigned short* vbuf = vLds[buf];
    f32x4 s2[4];
#pragma unroll
    for (int tt = 0; tt < 4; tt++) s2[tt] = (f32x4){0.f, 0.f, 0.f, 0.f};
#pragma unroll
    for (int tt = 0; tt < 4; tt++)
#pragma unroll
      for (int m = 0; m < 4; m++) {
        bf16x8 kf = *(const bf16x8*)&kbuf[(tt * 16 + lr) * 128 + ((m * 4 + lg) ^ lr7) * 8];
        s2[tt] = __builtin_amdgcn_mfma_f32_16x16x32_bf16(aq[m], kf, s2[tt], 0, 0, 0);
      }
    float tm = -3.0e38f;
#pragma unroll
    for (int tt = 0; tt < 4; tt++)
#pragma unroll
      for (int i = 0; i < 4; i++) tm = fmaxf(tm, s2[tt][i]);
#pragma unroll
    for (int d = 1; d < 64; d <<= 1) tm = fmaxf(tm, __shfl_xor(tm, d, 64));
    tm *= sc;
    if (tm > M + 8.0f) {
      float r = exp2f((M - tm) * L2E);
      M = tm;
#pragma unroll
      for (int o = 0; o < 8; o++)
#pragma unroll
        for (int i = 0; i < 4; i++) acc[o][i] *= r;
#pragma unroll
      for (int i = 0; i < 4; i++) lsum[i] *= r;
    }
    float ea = sc * L2E, eb = -M * L2E;
#pragma unroll
    for (int tt = 0; tt < 4; tt++)
#pragma unroll
      for (int i = 0; i < 4; i++) {
        float p = exp2f(fmaf(s2[tt][i], ea, eb));
        lsum[i] += p;
        pl[w][lg * 4 + i][tt * 16 + lr] = f2bf(p);
      }
    bf16x8 ap0 = *(const bf16x8*)&pl[w][lr][lg * 8];
    bf16x8 ap1 = *(const bf16x8*)&pl[w][lr][32 + lg * 8];
#pragma unroll
    for (int o = 0; o < 8; o++) {
      bf16x8 vf0 = *(const bf16x8*)&vbuf[(o * 16 + lr) * 64 + (lg ^ lr7) * 8];
      bf16x8 vf1 = *(const bf16x8*)&vbuf[(o * 16 + lr) * 64 + ((4 + lg) ^ lr7) * 8];
      acc[o] = __builtin_amdgcn_mfma_f32_16x16x32_bf16(ap0, vf0, acc[o], 0, 0, 0);
      acc[o] = __builtin_amdgcn_mfma_f32_16x16x32_bf16(ap1, vf1, acc[o], 0, 0, 0);
    }
  };

  stage(0, 0);
  __syncthreads();
  for (int kt = 0; kt < NT; kt += 2) {
    stage(kt + 1, 1);
    compute(0);
    __syncthreads();
    if (kt + 2 < NT) stage(kt + 2, 0);
    compute(1);
    __syncthreads();
  }

#pragma unroll
  for (int i = 0; i < 4; i++) {
#pragma unroll
    for (int d = 1; d < 16; d <<= 1) lsum[i] += __shfl_xor(lsum[i], d, 64);
    lsum[i] = 1.f / lsum[i];
  }
#pragma unroll
  for (int o = 0; o < 8; o++) {
    int col = h * 128 + o * 16 + lr;
#pragma unroll
    for (int i = 0; i < 4; i++) {
      int r = q0 + w * 16 + lg * 4 + i;
      out[(size_t)r * 3072 + col] = acc[o][i] * lsum[i];
    }
  }
}

extern "C" void kernel_launch(void* const* d_in, const int* in_sizes, int n_in,
                              void* d_out, int out_size, void* d_ws, size_t ws_size,
                              hipStream_t stream) {
  const float* hs  = (const float*)d_in[0];
  const float* Wq  = (const float*)d_in[1];
  const float* bq  = (const float*)d_in[2];
  const float* Wk  = (const float*)d_in[3];
  const float* bk  = (const float*)d_in[4];
  const float* Wv  = (const float*)d_in[5];
  const float* bv  = (const float*)d_in[6];
  const float* k_down = (const float*)d_in[9];
  const float* k_up   = (const float*)d_in[10];
  const float* v_down = (const float*)d_in[11];
  const float* v_up   = (const float*)d_in[12];
  const float* nqw = (const float*)d_in[13];
  const float* nkw = (const float*)d_in[14];
  const float* rc  = (const float*)d_in[15];
  const float* rsn = (const float*)d_in[16];
  float* out = (float*)d_out;

  char* ws = (char*)d_ws;
  unsigned short* hsb = (unsigned short*)(ws + 0);          // 13,369,344 B
  unsigned short* wb  = (unsigned short*)(ws + 13369344);   // 56,623,104 B
  float*          qkv = (float*)(ws + 69992448);            // 80,216,064 B
  unsigned short* qh  = (unsigned short*)(ws + 150208512);  //  7,077,888 B
  unsigned short* kh  = (unsigned short*)(ws + 157286400);  // 13,369,344 B
  unsigned short* vtb = (unsigned short*)(ws + 170655744);  // 13,369,344 B

  const int n8_hs = Sq * Dm / 8;
  const int n8_w  = Dm * Dm / 8;
  cvt_kernel<<<dim3((n8_hs + 255) / 256), 256, 0, stream>>>(hs, hsb, n8_hs);
  cvt3_kernel<<<dim3((n8_w + 255) / 256, 3), 256, 0, stream>>>(Wq, Wk, Wv, wb, n8_w);

  gemm_kernel<<<dim3(1032), 256, 0, stream>>>(hsb, wb, bq, bk, bv, qkv);
  lora_kernel<<<dim3(Sq - BLKR), 256, 0, stream>>>(hs, k_down, k_up, v_down, v_up, qkv);
  prep_kernel<<<dim3(Sq, NH), 64, 0, stream>>>(qkv, nqw, nkw, rc, rsn, qh, kh);
  vt_kernel<<<dim3(Sq / 32, HDm / 32, NH), 256, 0, stream>>>(qkv, vtb);
  attn_kernel<<<dim3(18 * NH), 256, 0, stream>>>(qh, kh, vtb, out);
}

// Round 7
// 365.404 us; speedup vs baseline: 1.0970x; 1.0953x over previous
//
#include <hip/hip_runtime.h>
#include <stdint.h>

#define Sq   2176
#define Dm   3072
#define NDm  9216
#define NH   24
#define HDm  128
#define BLKR 1152   // S - COND
#define NT   (Sq / 64)   // 34 KV tiles of 64

typedef __attribute__((ext_vector_type(8))) __bf16 bf16x8;
typedef __attribute__((ext_vector_type(4))) float f32x4;
typedef __attribute__((ext_vector_type(8))) unsigned short ushort8;

#define AS1 __attribute__((address_space(1)))
#define AS3 __attribute__((address_space(3)))

__device__ __forceinline__ unsigned short f2bf(float x) {
  unsigned u = __builtin_bit_cast(unsigned, x);
  u += 0x7FFFu + ((u >> 16) & 1u);   // RNE; inputs are finite randoms
  return (unsigned short)(u >> 16);
}

// ---------------- f32 -> bf16 conversion, 8 elems/thread ----------------
__global__ void cvt_kernel(const float* __restrict__ src,
                           unsigned short* __restrict__ dst, int n8) {
  int i = blockIdx.x * blockDim.x + threadIdx.x;
  if (i >= n8) return;
  const float4* s4 = (const float4*)src + (size_t)i * 2;
  float4 a = s4[0], b = s4[1];
  ushort8 o;
  o[0]=f2bf(a.x); o[1]=f2bf(a.y); o[2]=f2bf(a.z); o[3]=f2bf(a.w);
  o[4]=f2bf(b.x); o[5]=f2bf(b.y); o[6]=f2bf(b.z); o[7]=f2bf(b.w);
  *((ushort8*)dst + i) = o;
}

// 3 weight matrices in one launch (blockIdx.y selects source)
__global__ void cvt3_kernel(const float* __restrict__ w0, const float* __restrict__ w1,
                            const float* __restrict__ w2,
                            unsigned short* __restrict__ dst, int n8) {
  int i = blockIdx.x * blockDim.x + threadIdx.x;
  if (i >= n8) return;
  const float* src = blockIdx.y == 0 ? w0 : (blockIdx.y == 1 ? w1 : w2);
  const float4* s4 = (const float4*)src + (size_t)i * 2;
  float4 a = s4[0], b = s4[1];
  ushort8 o;
  o[0]=f2bf(a.x); o[1]=f2bf(a.y); o[2]=f2bf(a.z); o[3]=f2bf(a.w);
  o[4]=f2bf(b.x); o[5]=f2bf(b.y); o[6]=f2bf(b.z); o[7]=f2bf(b.w);
  *((ushort8*)dst + (size_t)blockIdx.y * (Dm * (size_t)Dm / 8) + i) = o;
}

// ---------------- fused QKV GEMM: C[s][n] = sum_e hs[s][e]*W[n][e] + bias ---
// 128x128 tile, 4 waves, BK=64 (48 iters: half the barrier drains of BK=32).
// 2-barrier single-buffer structure (round-4 measured best), per-row
// involution swizzle u^=(r&7) on 16B units (conflict-free both sides),
// dead-Q-block skip + round-4 chunk mapping (fetch 111MB measured).
__global__ __launch_bounds__(256) void gemm_kernel(
    const unsigned short* __restrict__ A,
    const unsigned short* __restrict__ B,
    const float* __restrict__ bq, const float* __restrict__ bk,
    const float* __restrict__ bv, float* __restrict__ C) {
  __shared__ __attribute__((aligned(16))) unsigned short aL[128 * 64];
  __shared__ __attribute__((aligned(16))) unsigned short bL[128 * 64];
  int t = threadIdx.x;
  int wid = t >> 6, lane = t & 63;
  int lr = lane & 15, lg = lane >> 4;
  int wr = wid >> 1, wc = wid & 1;

  // grid remap: 1032 blocks = 8 XCD chunks x 129 (round-4 proven mapping).
  // Q cols (nt 0..23): m-tiles 0..8 only (Q rows >=1152 are never read).
  int bid = blockIdx.x;
  int wg = (bid & 7) * 129 + (bid >> 3);
  int mt, nt;
  if (wg < 216) { nt = wg / 9; mt = wg % 9; }
  else { int r2 = wg - 216; nt = 24 + r2 / 17; mt = r2 % 17; }
  int m0 = mt * 128, n0 = nt * 128;

  f32x4 acc[4][4];
#pragma unroll
  for (int m = 0; m < 4; m++)
#pragma unroll
    for (int n = 0; n < 4; n++) acc[m][n] = (f32x4){0.f, 0.f, 0.f, 0.f};

  // staging sources. Storage 16B-unit g (row r=g>>3, slot g&7) holds logical
  // unit column u = (g&7)^(r&7) of row r (involution).
  const unsigned short* sA[4];
  const unsigned short* sB[4];
#pragma unroll
  for (int c = 0; c < 4; c++) {
    int g = c * 256 + t;
    int r = g >> 3, u = (g & 7) ^ (r & 7);
    sA[c] = A + (size_t)(m0 + r) * Dm + u * 8;
    sB[c] = B + (size_t)(n0 + r) * Dm + u * 8;
  }

  // ds_read offsets (elems): logical (row R, unit kk*4+lg) -> storage
  int offA[4][2], offB[4][2];
#pragma unroll
  for (int m = 0; m < 4; m++) {
    int R = wr * 64 + m * 16 + lr;
#pragma unroll
    for (int kk = 0; kk < 2; kk++)
      offA[m][kk] = (R * 8 + ((kk * 4 + lg) ^ (R & 7))) * 8;
  }
#pragma unroll
  for (int n = 0; n < 4; n++) {
    int R = wc * 64 + n * 16 + lr;
#pragma unroll
    for (int kk = 0; kk < 2; kk++)
      offB[n][kk] = (R * 8 + ((kk * 4 + lg) ^ (R & 7))) * 8;
  }

  for (int kt = 0; kt < Dm / 64; kt++) {
    const int ko = kt * 64;
#pragma unroll
    for (int c = 0; c < 4; c++) {
      __builtin_amdgcn_global_load_lds(
          (const AS1 void*)(sA[c] + ko),
          (AS3 void*)(&aL[c * 2048 + wid * 512]), 16, 0, 0);
      __builtin_amdgcn_global_load_lds(
          (const AS1 void*)(sB[c] + ko),
          (AS3 void*)(&bL[c * 2048 + wid * 512]), 16, 0, 0);
    }
    __syncthreads();   // drain: tile ready (once per 64-K step now)

    bf16x8 a0[4], b0[4];
#pragma unroll
    for (int m = 0; m < 4; m++) a0[m] = *(const bf16x8*)&aL[offA[m][0]];
#pragma unroll
    for (int n = 0; n < 4; n++) b0[n] = *(const bf16x8*)&bL[offB[n][0]];
#pragma unroll
    for (int m = 0; m < 4; m++)
#pragma unroll
      for (int n = 0; n < 4; n++)
        acc[m][n] = __builtin_amdgcn_mfma_f32_16x16x32_bf16(a0[m], b0[n], acc[m][n], 0, 0, 0);

    bf16x8 a1[4], b1[4];
#pragma unroll
    for (int m = 0; m < 4; m++) a1[m] = *(const bf16x8*)&aL[offA[m][1]];
#pragma unroll
    for (int n = 0; n < 4; n++) b1[n] = *(const bf16x8*)&bL[offB[n][1]];
#pragma unroll
    for (int m = 0; m < 4; m++)
#pragma unroll
      for (int n = 0; n < 4; n++)
        acc[m][n] = __builtin_amdgcn_mfma_f32_16x16x32_bf16(a1[m], b1[n], acc[m][n], 0, 0, 0);
    __syncthreads();   // protect LDS before next stage
  }

#pragma unroll
  for (int m = 0; m < 4; m++)
#pragma unroll
    for (int n = 0; n < 4; n++) {
      int col = n0 + wc * 64 + n * 16 + lr;
      float bias = col < 3072 ? bq[col] : (col < 6144 ? bk[col - 3072] : bv[col - 6144]);
#pragma unroll
      for (int i = 0; i < 4; i++) {
        int r = m0 + wr * 64 + m * 16 + lg * 4 + i;
        C[(size_t)r * NDm + col] = acc[m][n][i] + bias;
      }
    }
}

// ---------------- LoRA for k,v only (q LoRA only touches discarded rows) ---
__global__ __launch_bounds__(256) void lora_kernel(
    const float* __restrict__ hs,
    const float* __restrict__ k_down, const float* __restrict__ k_up,
    const float* __restrict__ v_down, const float* __restrict__ v_up,
    float* __restrict__ qkv) {
  int srow = BLKR + blockIdx.x;
  int t = threadIdx.x;
  __shared__ float hsl[Dm];
  __shared__ float tl[32];
  for (int e = t; e < Dm; e += 256) hsl[e] = hs[(size_t)srow * Dm + e];
  __syncthreads();
  int dot = t >> 3, part = t & 7;
  int mat = dot >> 4, j = dot & 15;
  const float* down = mat ? v_down : k_down;
  float p = 0.f;
  for (int e = part; e < Dm; e += 8) p += hsl[e] * down[j * Dm + e];
  p += __shfl_xor(p, 1, 64);
  p += __shfl_xor(p, 2, 64);
  p += __shfl_xor(p, 4, 64);
  if (part == 0) tl[dot] = p;
  __syncthreads();
  float tk[16], tv[16];
#pragma unroll
  for (int jj = 0; jj < 16; jj++) { tk[jj] = tl[jj]; tv[jj] = tl[16 + jj]; }
  for (int n = t; n < Dm; n += 256) {
    float ak = 0.f, av = 0.f;
#pragma unroll
    for (int jj = 0; jj < 16; jj++) {
      ak += tk[jj] * k_up[n * 16 + jj];
      av += tv[jj] * v_up[n * 16 + jj];
    }
    qkv[(size_t)srow * NDm + 3072 + n] += ak;
    qkv[(size_t)srow * NDm + 6144 + n] += av;
  }
}

// ---------------- RMSNorm + RoPE -> bf16 head-major q,k ----------------
// one block (4 waves) per row s; wave w handles heads w*6..w*6+5.
// RoPE cos/sin loaded once per s (reused across all 24 heads).
__global__ __launch_bounds__(256) void prep_kernel(
    const float* __restrict__ qkv,
    const float* __restrict__ nqw, const float* __restrict__ nkw,
    const float* __restrict__ rc, const float* __restrict__ rs,
    unsigned short* __restrict__ qh, unsigned short* __restrict__ kh) {
  int s = blockIdx.x;
  int w = threadIdx.x >> 6, l = threadIdx.x & 63;
  int d0 = l * 2;
  float c0 = rc[s * 128 + d0], c1 = rc[s * 128 + d0 + 1];
  float s0 = rs[s * 128 + d0], s1 = rs[s * 128 + d0 + 1];
  float wk0 = nkw[d0], wk1 = nkw[d0 + 1];
  float wq0 = nqw[d0], wq1 = nqw[d0 + 1];
  bool doq = (s < BLKR);

#pragma unroll
  for (int hh = 0; hh < 6; hh++) {
    int h = w * 6 + hh;
    { // k: all rows
      const float* kp = qkv + (size_t)s * NDm + 3072 + h * 128;
      float2 x = *(const float2*)(kp + d0);
      float ss = x.x * x.x + x.y * x.y;
#pragma unroll
      for (int m = 1; m < 64; m <<= 1) ss += __shfl_xor(ss, m, 64);
      float r = rsqrtf(ss * (1.f / 128.f) + 1e-6f);
      float xn0 = x.x * r * wk0, xn1 = x.y * r * wk1;
      ushort2 o = make_ushort2(f2bf(xn0 * c0 - xn1 * s0), f2bf(xn1 * c1 + xn0 * s1));
      *(ushort2*)&kh[((size_t)h * Sq + s) * 128 + d0] = o;
    }
    if (doq) { // q: only output rows
      const float* qp = qkv + (size_t)s * NDm + h * 128;
      float2 x = *(const float2*)(qp + d0);
      float ss = x.x * x.x + x.y * x.y;
#pragma unroll
      for (int m = 1; m < 64; m <<= 1) ss += __shfl_xor(ss, m, 64);
      float r = rsqrtf(ss * (1.f / 128.f) + 1e-6f);
      float xn0 = x.x * r * wq0, xn1 = x.y * r * wq1;
      ushort2 o = make_ushort2(f2bf(xn0 * c0 - xn1 * s0), f2bf(xn1 * c1 + xn0 * s1));
      *(ushort2*)&qh[((size_t)h * BLKR + s) * 128 + d0] = o;
    }
  }
}

// ---------------- v transpose to V^T per head (bf16) ----------------
__global__ __launch_bounds__(256) void vt_kernel(const float* __restrict__ qkv,
                                                 unsigned short* __restrict__ vt) {
  int st = blockIdx.x, dt = blockIdx.y, h = blockIdx.z;
  int tx = threadIdx.x & 31, ty = threadIdx.x >> 5;
  __shared__ float ld[32][33];
  int s0 = st * 32, d0 = dt * 32;
#pragma unroll
  for (int p = 0; p < 4; p++) {
    int ss = ty + p * 8;
    ld[ss][tx] = qkv[(size_t)(s0 + ss) * NDm + 6144 + h * 128 + d0 + tx];
  }
  __syncthreads();
#pragma unroll
  for (int p = 0; p < 4; p++) {
    int dd = ty + p * 8;
    vt[((size_t)h * 128 + d0 + dd) * Sq + s0 + tx] = f2bf(ld[tx][dd]);
  }
}

// ---------------- flash attention: LDS-staged, double-buffered ----------
__global__ __launch_bounds__(256) void attn_kernel(
    const unsigned short* __restrict__ qh,  // [NH][1152][128]
    const unsigned short* __restrict__ kh,  // [NH][2176][128]
    const unsigned short* __restrict__ vt,  // [NH][128][2176]
    float* __restrict__ out) {              // [1152][3072] f32
  int id = blockIdx.x;
  int wg = (id & 7) * 54 + (id >> 3);
  int h = wg / 18, qt = wg % 18;
  int q0 = qt * 64;

  int t = threadIdx.x;
  int w = t >> 6, lane = t & 63;
  int lr = lane & 15, lg = lane >> 4;

  __shared__ __attribute__((aligned(16))) unsigned short kLds[2][64 * 128];
  __shared__ __attribute__((aligned(16))) unsigned short vLds[2][128 * 64];
  __shared__ __attribute__((aligned(16))) unsigned short pl[4][16][72];

  const unsigned short* qb = qh + ((size_t)h * BLKR + q0 + w * 16) * 128;
  bf16x8 aq[4];
#pragma unroll
  for (int m = 0; m < 4; m++)
    aq[m] = *(const bf16x8*)(qb + (size_t)lr * 128 + m * 32 + lg * 8);

  const unsigned short* kh_h = kh + (size_t)h * Sq * 128;
  const unsigned short* vt_h = vt + (size_t)h * 128 * Sq;
  int l16 = lane >> 4, s16 = lane & 15;
  int l8 = lane >> 3, s8 = lane & 7;
  const unsigned short* srcK[4];
  const unsigned short* srcV[4];
  int kRowB[4], vRowB[4];
#pragma unroll
  for (int c = 0; c < 4; c++) {
    int rK = w * 16 + c * 4 + l16;
    srcK[c] = kh_h + (size_t)rK * 128 + ((s16 ^ (rK & 7)) * 8);
    kRowB[c] = (w * 16 + c * 4) * 128;
    int rV = (w * 4 + c) * 8 + l8;
    srcV[c] = vt_h + (size_t)rV * Sq + ((s8 ^ (rV & 7)) * 8);
    vRowB[c] = (w * 4 + c) * 512;
  }

  auto stage = [&](int kt, int buf) {
#pragma unroll
    for (int c = 0; c < 4; c++)
      __builtin_amdgcn_global_load_lds(
          (const AS1 void*)(srcK[c] + (size_t)kt * 8192),
          (AS3 void*)(&kLds[buf][kRowB[c]]), 16, 0, 0);
#pragma unroll
    for (int c = 0; c < 4; c++)
      __builtin_amdgcn_global_load_lds(
          (const AS1 void*)(srcV[c] + (size_t)kt * 64),
          (AS3 void*)(&vLds[buf][vRowB[c]]), 16, 0, 0);
  };

  f32x4 acc[8];
#pragma unroll
  for (int o = 0; o < 8; o++) acc[o] = (f32x4){0.f, 0.f, 0.f, 0.f};
  float lsum[4] = {0.f, 0.f, 0.f, 0.f};
  float M = -3.0e38f;
  const float sc = 0.08838834764831845f;
  const float L2E = 1.4426950408889634f;

  int lr7 = lr & 7;

  auto compute = [&](int buf) {
    const unsigned short* kbuf = kLds[buf];
    const unsigned short* vbuf = vLds[buf];
    f32x4 s2[4];
#pragma unroll
    for (int tt = 0; tt < 4; tt++) s2[tt] = (f32x4){0.f, 0.f, 0.f, 0.f};
#pragma unroll
    for (int tt = 0; tt < 4; tt++)
#pragma unroll
      for (int m = 0; m < 4; m++) {
        bf16x8 kf = *(const bf16x8*)&kbuf[(tt * 16 + lr) * 128 + ((m * 4 + lg) ^ lr7) * 8];
        s2[tt] = __builtin_amdgcn_mfma_f32_16x16x32_bf16(aq[m], kf, s2[tt], 0, 0, 0);
      }
    float tm = -3.0e38f;
#pragma unroll
    for (int tt = 0; tt < 4; tt++)
#pragma unroll
      for (int i = 0; i < 4; i++) tm = fmaxf(tm, s2[tt][i]);
#pragma unroll
    for (int d = 1; d < 64; d <<= 1) tm = fmaxf(tm, __shfl_xor(tm, d, 64));
    tm *= sc;
    if (tm > M + 8.0f) {
      float r = exp2f((M - tm) * L2E);
      M = tm;
#pragma unroll
      for (int o = 0; o < 8; o++)
#pragma unroll
        for (int i = 0; i < 4; i++) acc[o][i] *= r;
#pragma unroll
      for (int i = 0; i < 4; i++) lsum[i] *= r;
    }
    float ea = sc * L2E, eb = -M * L2E;
#pragma unroll
    for (int tt = 0; tt < 4; tt++)
#pragma unroll
      for (int i = 0; i < 4; i++) {
        float p = exp2f(fmaf(s2[tt][i], ea, eb));
        lsum[i] += p;
        pl[w][lg * 4 + i][tt * 16 + lr] = f2bf(p);
      }
    bf16x8 ap0 = *(const bf16x8*)&pl[w][lr][lg * 8];
    bf16x8 ap1 = *(const bf16x8*)&pl[w][lr][32 + lg * 8];
#pragma unroll
    for (int o = 0; o < 8; o++) {
      bf16x8 vf0 = *(const bf16x8*)&vbuf[(o * 16 + lr) * 64 + (lg ^ lr7) * 8];
      bf16x8 vf1 = *(const bf16x8*)&vbuf[(o * 16 + lr) * 64 + ((4 + lg) ^ lr7) * 8];
      acc[o] = __builtin_amdgcn_mfma_f32_16x16x32_bf16(ap0, vf0, acc[o], 0, 0, 0);
      acc[o] = __builtin_amdgcn_mfma_f32_16x16x32_bf16(ap1, vf1, acc[o], 0, 0, 0);
    }
  };

  stage(0, 0);
  __syncthreads();
  for (int kt = 0; kt < NT; kt += 2) {
    stage(kt + 1, 1);
    compute(0);
    __syncthreads();
    if (kt + 2 < NT) stage(kt + 2, 0);
    compute(1);
    __syncthreads();
  }

#pragma unroll
  for (int i = 0; i < 4; i++) {
#pragma unroll
    for (int d = 1; d < 16; d <<= 1) lsum[i] += __shfl_xor(lsum[i], d, 64);
    lsum[i] = 1.f / lsum[i];
  }
#pragma unroll
  for (int o = 0; o < 8; o++) {
    int col = h * 128 + o * 16 + lr;
#pragma unroll
    for (int i = 0; i < 4; i++) {
      int r = q0 + w * 16 + lg * 4 + i;
      out[(size_t)r * 3072 + col] = acc[o][i] * lsum[i];
    }
  }
}

extern "C" void kernel_launch(void* const* d_in, const int* in_sizes, int n_in,
                              void* d_out, int out_size, void* d_ws, size_t ws_size,
                              hipStream_t stream) {
  const float* hs  = (const float*)d_in[0];
  const float* Wq  = (const float*)d_in[1];
  const float* bq  = (const float*)d_in[2];
  const float* Wk  = (const float*)d_in[3];
  const float* bk  = (const float*)d_in[4];
  const float* Wv  = (const float*)d_in[5];
  const float* bv  = (const float*)d_in[6];
  const float* k_down = (const float*)d_in[9];
  const float* k_up   = (const float*)d_in[10];
  const float* v_down = (const float*)d_in[11];
  const float* v_up   = (const float*)d_in[12];
  const float* nqw = (const float*)d_in[13];
  const float* nkw = (const float*)d_in[14];
  const float* rc  = (const float*)d_in[15];
  const float* rsn = (const float*)d_in[16];
  float* out = (float*)d_out;

  char* ws = (char*)d_ws;
  unsigned short* hsb = (unsigned short*)(ws + 0);          // 13,369,344 B
  unsigned short* wb  = (unsigned short*)(ws + 13369344);   // 56,623,104 B
  float*          qkv = (float*)(ws + 69992448);            // 80,216,064 B
  unsigned short* qh  = (unsigned short*)(ws + 150208512);  //  7,077,888 B
  unsigned short* kh  = (unsigned short*)(ws + 157286400);  // 13,369,344 B
  unsigned short* vtb = (unsigned short*)(ws + 170655744);  // 13,369,344 B

  const int n8_hs = Sq * Dm / 8;
  const int n8_w  = Dm * Dm / 8;
  cvt_kernel<<<dim3((n8_hs + 255) / 256), 256, 0, stream>>>(hs, hsb, n8_hs);
  cvt3_kernel<<<dim3((n8_w + 255) / 256, 3), 256, 0, stream>>>(Wq, Wk, Wv, wb, n8_w);

  gemm_kernel<<<dim3(1032), 256, 0, stream>>>(hsb, wb, bq, bk, bv, qkv);
  lora_kernel<<<dim3(Sq - BLKR), 256, 0, stream>>>(hs, k_down, k_up, v_down, v_up, qkv);
  prep_kernel<<<dim3(Sq), 256, 0, stream>>>(qkv, nqw, nkw, rc, rsn, qh, kh);
  vt_kernel<<<dim3(Sq / 32, HDm / 32, NH), 256, 0, stream>>>(qkv, vtb);
  attn_kernel<<<dim3(18 * NH), 256, 0, stream>>>(qh, kh, vtb, out);
}

// Round 8
// 360.687 us; speedup vs baseline: 1.1114x; 1.0131x over previous
//
#include <hip/hip_runtime.h>
#include <stdint.h>

#define Sq   2176
#define Dm   3072
#define NDm  9216
#define NH   24
#define HDm  128
#define BLKR 1152   // S - COND
#define NT   (Sq / 64)   // 34 KV tiles of 64

typedef __attribute__((ext_vector_type(8))) __bf16 bf16x8;
typedef __attribute__((ext_vector_type(4))) float f32x4;
typedef __attribute__((ext_vector_type(8))) unsigned short ushort8;

#define AS1 __attribute__((address_space(1)))
#define AS3 __attribute__((address_space(3)))

__device__ __forceinline__ unsigned short f2bf(float x) {
  unsigned u = __builtin_bit_cast(unsigned, x);
  u += 0x7FFFu + ((u >> 16) & 1u);   // RNE; inputs are finite randoms
  return (unsigned short)(u >> 16);
}

// ---------------- f32 -> bf16 conversion, 8 elems/thread ----------------
__global__ void cvt_kernel(const float* __restrict__ src,
                           unsigned short* __restrict__ dst, int n8) {
  int i = blockIdx.x * blockDim.x + threadIdx.x;
  if (i >= n8) return;
  const float4* s4 = (const float4*)src + (size_t)i * 2;
  float4 a = s4[0], b = s4[1];
  ushort8 o;
  o[0]=f2bf(a.x); o[1]=f2bf(a.y); o[2]=f2bf(a.z); o[3]=f2bf(a.w);
  o[4]=f2bf(b.x); o[5]=f2bf(b.y); o[6]=f2bf(b.z); o[7]=f2bf(b.w);
  *((ushort8*)dst + i) = o;
}

// 3 weight matrices in one launch (blockIdx.y selects source)
__global__ void cvt3_kernel(const float* __restrict__ w0, const float* __restrict__ w1,
                            const float* __restrict__ w2,
                            unsigned short* __restrict__ dst, int n8) {
  int i = blockIdx.x * blockDim.x + threadIdx.x;
  if (i >= n8) return;
  const float* src = blockIdx.y == 0 ? w0 : (blockIdx.y == 1 ? w1 : w2);
  const float4* s4 = (const float4*)src + (size_t)i * 2;
  float4 a = s4[0], b = s4[1];
  ushort8 o;
  o[0]=f2bf(a.x); o[1]=f2bf(a.y); o[2]=f2bf(a.z); o[3]=f2bf(a.w);
  o[4]=f2bf(b.x); o[5]=f2bf(b.y); o[6]=f2bf(b.z); o[7]=f2bf(b.w);
  *((ushort8*)dst + (size_t)blockIdx.y * (Dm * (size_t)Dm / 8) + i) = o;
}

// ---------------- fused QKV GEMM: C[s][n] = sum_e hs[s][e]*W[n][e] + bias ---
// 128x128 tile, 4 waves, BK=64, 2-barrier single-buffer (round-7: 717 TF).
// This round: register-lean addressing (2 staging ptrs, 2 ds-read bases +
// imm offsets) + __launch_bounds__(256,4) -> VGPR<=64 + 64 AGPR = 128
// unified -> 4 blocks/CU (was 2) to hide the per-iter vmcnt drain.
__global__ __launch_bounds__(256, 4) void gemm_kernel(
    const unsigned short* __restrict__ A,
    const unsigned short* __restrict__ B,
    const float* __restrict__ bq, const float* __restrict__ bk,
    const float* __restrict__ bv, float* __restrict__ C) {
  __shared__ __attribute__((aligned(16))) unsigned short aL[128 * 64];
  __shared__ __attribute__((aligned(16))) unsigned short bL[128 * 64];
  int t = threadIdx.x;
  int wid = t >> 6, lane = t & 63;
  int lr = lane & 15, lg = lane >> 4;
  int wr = wid >> 1, wc = wid & 1;

  // grid remap: 1032 blocks = 8 XCD chunks x 129 (round-4 proven mapping).
  // Q cols (nt 0..23): m-tiles 0..8 only (Q rows >=1152 are never read).
  int bid = blockIdx.x;
  int wg = (bid & 7) * 129 + (bid >> 3);
  int mt, nt;
  if (wg < 216) { nt = wg / 9; mt = wg % 9; }
  else { int r2 = wg - 216; nt = 24 + r2 / 17; mt = r2 % 17; }
  int m0 = mt * 128, n0 = nt * 128;

  f32x4 acc[4][4];
#pragma unroll
  for (int m = 0; m < 4; m++)
#pragma unroll
    for (int n = 0; n < 4; n++) acc[m][n] = (f32x4){0.f, 0.f, 0.f, 0.f};

  // staging sources. Storage 16B-unit g (row r=g>>3, slot g&7) holds logical
  // unit u = (g&7)^(r&7). Since c*32 = 0 mod 8, u is c-invariant -> ONE
  // pointer per matrix, stride c*32*Dm.
  int tr = t >> 3;
  int uu = (t & 7) ^ (tr & 7);
  const unsigned short* pA = A + (size_t)(m0 + tr) * Dm + uu * 8;
  const unsigned short* pB = B + (size_t)(n0 + tr) * Dm + uu * 8;

  // ds_read bases (elems): logical (row R, unit kk*4+lg); R&7 == lr&7 for
  // all m -> swizzle term m-invariant; m contributes imm offset m*1024.
  int lr7 = lr & 7;
  int baseA = (wr * 64 + lr) * 64;
  int baseB = (wc * 64 + lr) * 64;
  int d0 = (lg ^ lr7) * 8;
  int d1 = ((4 + lg) ^ lr7) * 8;

  for (int kt = 0; kt < Dm / 64; kt++) {
    const int ko = kt * 64;
#pragma unroll
    for (int c = 0; c < 4; c++) {
      __builtin_amdgcn_global_load_lds(
          (const AS1 void*)(pA + (size_t)c * 32 * Dm + ko),
          (AS3 void*)(&aL[c * 2048 + wid * 512]), 16, 0, 0);
      __builtin_amdgcn_global_load_lds(
          (const AS1 void*)(pB + (size_t)c * 32 * Dm + ko),
          (AS3 void*)(&bL[c * 2048 + wid * 512]), 16, 0, 0);
    }
    __syncthreads();   // drain: tile ready (once per 64-K step)

    bf16x8 a0[4], b0[4];
#pragma unroll
    for (int m = 0; m < 4; m++) a0[m] = *(const bf16x8*)&aL[baseA + m * 1024 + d0];
#pragma unroll
    for (int n = 0; n < 4; n++) b0[n] = *(const bf16x8*)&bL[baseB + n * 1024 + d0];
#pragma unroll
    for (int m = 0; m < 4; m++)
#pragma unroll
      for (int n = 0; n < 4; n++)
        acc[m][n] = __builtin_amdgcn_mfma_f32_16x16x32_bf16(a0[m], b0[n], acc[m][n], 0, 0, 0);

    bf16x8 a1[4], b1[4];
#pragma unroll
    for (int m = 0; m < 4; m++) a1[m] = *(const bf16x8*)&aL[baseA + m * 1024 + d1];
#pragma unroll
    for (int n = 0; n < 4; n++) b1[n] = *(const bf16x8*)&bL[baseB + n * 1024 + d1];
#pragma unroll
    for (int m = 0; m < 4; m++)
#pragma unroll
      for (int n = 0; n < 4; n++)
        acc[m][n] = __builtin_amdgcn_mfma_f32_16x16x32_bf16(a1[m], b1[n], acc[m][n], 0, 0, 0);
    __syncthreads();   // protect LDS before next stage
  }

#pragma unroll
  for (int m = 0; m < 4; m++)
#pragma unroll
    for (int n = 0; n < 4; n++) {
      int col = n0 + wc * 64 + n * 16 + lr;
      float bias = col < 3072 ? bq[col] : (col < 6144 ? bk[col - 3072] : bv[col - 6144]);
#pragma unroll
      for (int i = 0; i < 4; i++) {
        int r = m0 + wr * 64 + m * 16 + lg * 4 + i;
        C[(size_t)r * NDm + col] = acc[m][n][i] + bias;
      }
    }
}

// ---------------- LoRA for k,v only (q LoRA only touches discarded rows) ---
__global__ __launch_bounds__(256) void lora_kernel(
    const float* __restrict__ hs,
    const float* __restrict__ k_down, const float* __restrict__ k_up,
    const float* __restrict__ v_down, const float* __restrict__ v_up,
    float* __restrict__ qkv) {
  int srow = BLKR + blockIdx.x;
  int t = threadIdx.x;
  __shared__ float hsl[Dm];
  __shared__ float tl[32];
  for (int e = t; e < Dm; e += 256) hsl[e] = hs[(size_t)srow * Dm + e];
  __syncthreads();
  int dot = t >> 3, part = t & 7;
  int mat = dot >> 4, j = dot & 15;
  const float* down = mat ? v_down : k_down;
  float p = 0.f;
  for (int e = part; e < Dm; e += 8) p += hsl[e] * down[j * Dm + e];
  p += __shfl_xor(p, 1, 64);
  p += __shfl_xor(p, 2, 64);
  p += __shfl_xor(p, 4, 64);
  if (part == 0) tl[dot] = p;
  __syncthreads();
  float tk[16], tv[16];
#pragma unroll
  for (int jj = 0; jj < 16; jj++) { tk[jj] = tl[jj]; tv[jj] = tl[16 + jj]; }
  for (int n = t; n < Dm; n += 256) {
    float ak = 0.f, av = 0.f;
#pragma unroll
    for (int jj = 0; jj < 16; jj++) {
      ak += tk[jj] * k_up[n * 16 + jj];
      av += tv[jj] * v_up[n * 16 + jj];
    }
    qkv[(size_t)srow * NDm + 3072 + n] += ak;
    qkv[(size_t)srow * NDm + 6144 + n] += av;
  }
}

// ---------------- RMSNorm + RoPE -> bf16 head-major q,k ----------------
// one block (4 waves) per row s; wave w handles heads w*6..w*6+5.
__global__ __launch_bounds__(256) void prep_kernel(
    const float* __restrict__ qkv,
    const float* __restrict__ nqw, const float* __restrict__ nkw,
    const float* __restrict__ rc, const float* __restrict__ rs,
    unsigned short* __restrict__ qh, unsigned short* __restrict__ kh) {
  int s = blockIdx.x;
  int w = threadIdx.x >> 6, l = threadIdx.x & 63;
  int d0 = l * 2;
  float c0 = rc[s * 128 + d0], c1 = rc[s * 128 + d0 + 1];
  float s0 = rs[s * 128 + d0], s1 = rs[s * 128 + d0 + 1];
  float wk0 = nkw[d0], wk1 = nkw[d0 + 1];
  float wq0 = nqw[d0], wq1 = nqw[d0 + 1];
  bool doq = (s < BLKR);

#pragma unroll
  for (int hh = 0; hh < 6; hh++) {
    int h = w * 6 + hh;
    { // k: all rows
      const float* kp = qkv + (size_t)s * NDm + 3072 + h * 128;
      float2 x = *(const float2*)(kp + d0);
      float ss = x.x * x.x + x.y * x.y;
#pragma unroll
      for (int m = 1; m < 64; m <<= 1) ss += __shfl_xor(ss, m, 64);
      float r = rsqrtf(ss * (1.f / 128.f) + 1e-6f);
      float xn0 = x.x * r * wk0, xn1 = x.y * r * wk1;
      ushort2 o = make_ushort2(f2bf(xn0 * c0 - xn1 * s0), f2bf(xn1 * c1 + xn0 * s1));
      *(ushort2*)&kh[((size_t)h * Sq + s) * 128 + d0] = o;
    }
    if (doq) { // q: only output rows
      const float* qp = qkv + (size_t)s * NDm + h * 128;
      float2 x = *(const float2*)(qp + d0);
      float ss = x.x * x.x + x.y * x.y;
#pragma unroll
      for (int m = 1; m < 64; m <<= 1) ss += __shfl_xor(ss, m, 64);
      float r = rsqrtf(ss * (1.f / 128.f) + 1e-6f);
      float xn0 = x.x * r * wq0, xn1 = x.y * r * wq1;
      ushort2 o = make_ushort2(f2bf(xn0 * c0 - xn1 * s0), f2bf(xn1 * c1 + xn0 * s1));
      *(ushort2*)&qh[((size_t)h * BLKR + s) * 128 + d0] = o;
    }
  }
}

// ---------------- v transpose to V^T per head (bf16) ----------------
__global__ __launch_bounds__(256) void vt_kernel(const float* __restrict__ qkv,
                                                 unsigned short* __restrict__ vt) {
  int st = blockIdx.x, dt = blockIdx.y, h = blockIdx.z;
  int tx = threadIdx.x & 31, ty = threadIdx.x >> 5;
  __shared__ float ld[32][33];
  int s0 = st * 32, d0 = dt * 32;
#pragma unroll
  for (int p = 0; p < 4; p++) {
    int ss = ty + p * 8;
    ld[ss][tx] = qkv[(size_t)(s0 + ss) * NDm + 6144 + h * 128 + d0 + tx];
  }
  __syncthreads();
#pragma unroll
  for (int p = 0; p < 4; p++) {
    int dd = ty + p * 8;
    vt[((size_t)h * 128 + d0 + dd) * Sq + s0 + tx] = f2bf(ld[tx][dd]);
  }
}

// ---------------- flash attention: LDS-staged, double-buffered ----------
__global__ __launch_bounds__(256) void attn_kernel(
    const unsigned short* __restrict__ qh,  // [NH][1152][128]
    const unsigned short* __restrict__ kh,  // [NH][2176][128]
    const unsigned short* __restrict__ vt,  // [NH][128][2176]
    float* __restrict__ out) {              // [1152][3072] f32
  int id = blockIdx.x;
  int wg = (id & 7) * 54 + (id >> 3);
  int h = wg / 18, qt = wg % 18;
  int q0 = qt * 64;

  int t = threadIdx.x;
  int w = t >> 6, lane = t & 63;
  int lr = lane & 15, lg = lane >> 4;

  __shared__ __attribute__((aligned(16))) unsigned short kLds[2][64 * 128];
  __shared__ __attribute__((aligned(16))) unsigned short vLds[2][128 * 64];
  __shared__ __attribute__((aligned(16))) unsigned short pl[4][16][72];

  const unsigned short* qb = qh + ((size_t)h * BLKR + q0 + w * 16) * 128;
  bf16x8 aq[4];
#pragma unroll
  for (int m = 0; m < 4; m++)
    aq[m] = *(const bf16x8*)(qb + (size_t)lr * 128 + m * 32 + lg * 8);

  const unsigned short* kh_h = kh + (size_t)h * Sq * 128;
  const unsigned short* vt_h = vt + (size_t)h * 128 * Sq;
  int l16 = lane >> 4, s16 = lane & 15;
  int l8 = lane >> 3, s8 = lane & 7;
  const unsigned short* srcK[4];
  const unsigned short* srcV[4];
  int kRowB[4], vRowB[4];
#pragma unroll
  for (int c = 0; c < 4; c++) {
    int rK = w * 16 + c * 4 + l16;
    srcK[c] = kh_h + (size_t)rK * 128 + ((s16 ^ (rK & 7)) * 8);
    kRowB[c] = (w * 16 + c * 4) * 128;
    int rV = (w * 4 + c) * 8 + l8;
    srcV[c] = vt_h + (size_t)rV * Sq + ((s8 ^ (rV & 7)) * 8);
    vRowB[c] = (w * 4 + c) * 512;
  }

  auto stage = [&](int kt, int buf) {
#pragma unroll
    for (int c = 0; c < 4; c++)
      __builtin_amdgcn_global_load_lds(
          (const AS1 void*)(srcK[c] + (size_t)kt * 8192),
          (AS3 void*)(&kLds[buf][kRowB[c]]), 16, 0, 0);
#pragma unroll
    for (int c = 0; c < 4; c++)
      __builtin_amdgcn_global_load_lds(
          (const AS1 void*)(srcV[c] + (size_t)kt * 64),
          (AS3 void*)(&vLds[buf][vRowB[c]]), 16, 0, 0);
  };

  f32x4 acc[8];
#pragma unroll
  for (int o = 0; o < 8; o++) acc[o] = (f32x4){0.f, 0.f, 0.f, 0.f};
  float lsum[4] = {0.f, 0.f, 0.f, 0.f};
  float M = -3.0e38f;
  const float sc = 0.08838834764831845f;
  const float L2E = 1.4426950408889634f;

  int lr7 = lr & 7;

  auto compute = [&](int buf) {
    const unsigned short* kbuf = kLds[buf];
    const unsigned short* vbuf = vLds[buf];
    f32x4 s2[4];
#pragma unroll
    for (int tt = 0; tt < 4; tt++) s2[tt] = (f32x4){0.f, 0.f, 0.f, 0.f};
#pragma unroll
    for (int tt = 0; tt < 4; tt++)
#pragma unroll
      for (int m = 0; m < 4; m++) {
        bf16x8 kf = *(const bf16x8*)&kbuf[(tt * 16 + lr) * 128 + ((m * 4 + lg) ^ lr7) * 8];
        s2[tt] = __builtin_amdgcn_mfma_f32_16x16x32_bf16(aq[m], kf, s2[tt], 0, 0, 0);
      }
    float tm = -3.0e38f;
#pragma unroll
    for (int tt = 0; tt < 4; tt++)
#pragma unroll
      for (int i = 0; i < 4; i++) tm = fmaxf(tm, s2[tt][i]);
#pragma unroll
    for (int d = 1; d < 64; d <<= 1) tm = fmaxf(tm, __shfl_xor(tm, d, 64));
    tm *= sc;
    if (tm > M + 8.0f) {
      float r = exp2f((M - tm) * L2E);
      M = tm;
#pragma unroll
      for (int o = 0; o < 8; o++)
#pragma unroll
        for (int i = 0; i < 4; i++) acc[o][i] *= r;
#pragma unroll
      for (int i = 0; i < 4; i++) lsum[i] *= r;
    }
    float ea = sc * L2E, eb = -M * L2E;
#pragma unroll
    for (int tt = 0; tt < 4; tt++)
#pragma unroll
      for (int i = 0; i < 4; i++) {
        float p = exp2f(fmaf(s2[tt][i], ea, eb));
        lsum[i] += p;
        pl[w][lg * 4 + i][tt * 16 + lr] = f2bf(p);
      }
    bf16x8 ap0 = *(const bf16x8*)&pl[w][lr][lg * 8];
    bf16x8 ap1 = *(const bf16x8*)&pl[w][lr][32 + lg * 8];
#pragma unroll
    for (int o = 0; o < 8; o++) {
      bf16x8 vf0 = *(const bf16x8*)&vbuf[(o * 16 + lr) * 64 + (lg ^ lr7) * 8];
      bf16x8 vf1 = *(const bf16x8*)&vbuf[(o * 16 + lr) * 64 + ((4 + lg) ^ lr7) * 8];
      acc[o] = __builtin_amdgcn_mfma_f32_16x16x32_bf16(ap0, vf0, acc[o], 0, 0, 0);
      acc[o] = __builtin_amdgcn_mfma_f32_16x16x32_bf16(ap1, vf1, acc[o], 0, 0, 0);
    }
  };

  stage(0, 0);
  __syncthreads();
  for (int kt = 0; kt < NT; kt += 2) {
    stage(kt + 1, 1);
    compute(0);
    __syncthreads();
    if (kt + 2 < NT) stage(kt + 2, 0);
    compute(1);
    __syncthreads();
  }

#pragma unroll
  for (int i = 0; i < 4; i++) {
#pragma unroll
    for (int d = 1; d < 16; d <<= 1) lsum[i] += __shfl_xor(lsum[i], d, 64);
    lsum[i] = 1.f / lsum[i];
  }
#pragma unroll
  for (int o = 0; o < 8; o++) {
    int col = h * 128 + o * 16 + lr;
#pragma unroll
    for (int i = 0; i < 4; i++) {
      int r = q0 + w * 16 + lg * 4 + i;
      out[(size_t)r * 3072 + col] = acc[o][i] * lsum[i];
    }
  }
}

extern "C" void kernel_launch(void* const* d_in, const int* in_sizes, int n_in,
                              void* d_out, int out_size, void* d_ws, size_t ws_size,
                              hipStream_t stream) {
  const float* hs  = (const float*)d_in[0];
  const float* Wq  = (const float*)d_in[1];
  const float* bq  = (const float*)d_in[2];
  const float* Wk  = (const float*)d_in[3];
  const float* bk  = (const float*)d_in[4];
  const float* Wv  = (const float*)d_in[5];
  const float* bv  = (const float*)d_in[6];
  const float* k_down = (const float*)d_in[9];
  const float* k_up   = (const float*)d_in[10];
  const float* v_down = (const float*)d_in[11];
  const float* v_up   = (const float*)d_in[12];
  const float* nqw = (const float*)d_in[13];
  const float* nkw = (const float*)d_in[14];
  const float* rc  = (const float*)d_in[15];
  const float* rsn = (const float*)d_in[16];
  float* out = (float*)d_out;

  char* ws = (char*)d_ws;
  unsigned short* hsb = (unsigned short*)(ws + 0);          // 13,369,344 B
  unsigned short* wb  = (unsigned short*)(ws + 13369344);   // 56,623,104 B
  float*          qkv = (float*)(ws + 69992448);            // 80,216,064 B
  unsigned short* qh  = (unsigned short*)(ws + 150208512);  //  7,077,888 B
  unsigned short* kh  = (unsigned short*)(ws + 157286400);  // 13,369,344 B
  unsigned short* vtb = (unsigned short*)(ws + 170655744);  // 13,369,344 B

  const int n8_hs = Sq * Dm / 8;
  const int n8_w  = Dm * Dm / 8;
  cvt_kernel<<<dim3((n8_hs + 255) / 256), 256, 0, stream>>>(hs, hsb, n8_hs);
  cvt3_kernel<<<dim3((n8_w + 255) / 256, 3), 256, 0, stream>>>(Wq, Wk, Wv, wb, n8_w);

  gemm_kernel<<<dim3(1032), 256, 0, stream>>>(hsb, wb, bq, bk, bv, qkv);
  lora_kernel<<<dim3(Sq - BLKR), 256, 0, stream>>>(hs, k_down, k_up, v_down, v_up, qkv);
  prep_kernel<<<dim3(Sq), 256, 0, stream>>>(qkv, nqw, nkw, rc, rsn, qh, kh);
  vt_kernel<<<dim3(Sq / 32, HDm / 32, NH), 256, 0, stream>>>(qkv, vtb);
  attn_kernel<<<dim3(18 * NH), 256, 0, stream>>>(qh, kh, vtb, out);
}